// Round 10
// baseline (4731.370 us; speedup 1.0000x reference)
//
#include <hip/hip_runtime.h>
#include <hip/hip_bf16.h>
#include <stdint.h>

typedef __bf16 bf16x8 __attribute__((ext_vector_type(8)));
typedef float f32x4 __attribute__((ext_vector_type(4)));
typedef short short8 __attribute__((ext_vector_type(8)));
typedef unsigned long long u64;
typedef unsigned int u32;

#define B_ 32
#define T_ 512

// workspace layout (bytes)
#define CTL_OFF   0x0        // ctl[0]=cnt, [1]=cnt2, [2]=fallback, [4+l]=layer xcc
#define FLOC_OFF  0x1000     // local flags:  layer*0x800 + wg*64
#define FCRS_OFF  0x3000     // cross flags:  layer*0x800 + wg*64 (granularity 4 steps)
#define FING_OFF  0x5000     // inGEMM flags: (lc-1)*0x800 + w*64
#define LRING_OFF 0x100000   // local h rings: layer*0x100000, 16 slots x 64KB
#define XRING_OFF 0x400000   // cross h rings: l{0,1}*0x100000, 16 slots x 64KB (MALL)
#define ZRING_OFF 0x600000   // Zin rings f32: (lc-1)*0x800000, 16 slots x 512KB (MALL)
#define ZIN0_OFF  0x1600000  // 128MB bf16 (B*T,4096) layer-0 input gates
#define XA_OFF    0x9600000  // 32MB bf16 x
#define WIT_OFF   0xB600000  // 24MB bf16 Wi^T (L,4096,1024)
#define WHT_OFF   0xCE00000  // 24MB bf16 Wh^T (L,4096,1024)

__device__ inline unsigned short f2bf(float f) {
  unsigned u = __float_as_uint(f);
  unsigned r = (u + 0x7fffu + ((u >> 16) & 1u)) >> 16;
  return (unsigned short)r;
}
__device__ inline float bf2f(unsigned short h) {
  return __uint_as_float(((unsigned)h) << 16);
}
__device__ __forceinline__ float sigm(float x) { return 1.f / (1.f + __expf(-x)); }
__device__ __forceinline__ float tanh_(float x) {
  float e2 = __expf(-2.f * fabsf(x));
  return copysignf((1.f - e2) / (1.f + e2), x);
}

// local-L2 flag poll: atomic add-0 (atomics execute at TCC/L2, never served by L1)
__device__ __forceinline__ u32 poll_loc(u32* p) {
  u32 r, z = 0;
  asm volatile("global_atomic_add %0, %1, %2, off sc0\n\ts_waitcnt vmcnt(0)"
               : "=v"(r) : "v"(p), "v"(z) : "memory");
  return r;
}
__device__ __forceinline__ u32 ld_mall(const u32* p) {
  return __hip_atomic_load(p, __ATOMIC_RELAXED, __HIP_MEMORY_SCOPE_AGENT);
}
__device__ __forceinline__ void st_mallf(u32* p, u32 v) {
  __hip_atomic_store(p, v, __ATOMIC_RELAXED, __HIP_MEMORY_SCOPE_AGENT);
}
// write-through store (proven rounds 3-8 h-exchange primitive)
__device__ __forceinline__ void st_wt32(void* p, u32 v) {
  asm volatile("global_store_dword %0, %1, off sc0 sc1" :: "v"(p), "v"(v) : "memory");
}
__device__ __forceinline__ void st_wt64(void* p, u64 v) {
  asm volatile("global_store_dwordx2 %0, %1, off sc0 sc1" :: "v"(p), "v"(v) : "memory");
}

// ---------------- f32 -> bf16 convert ----------------
__global__ __launch_bounds__(256) void k_conv(const float* __restrict__ in,
                                              unsigned short* __restrict__ out, int n8) {
  int i = blockIdx.x * 256 + threadIdx.x;
  if (i >= n8) return;
  const float4* p = (const float4*)(in) + (size_t)i * 2;
  float4 a = p[0], b = p[1];
  short8 o;
  o[0] = (short)f2bf(a.x); o[1] = (short)f2bf(a.y); o[2] = (short)f2bf(a.z); o[3] = (short)f2bf(a.w);
  o[4] = (short)f2bf(b.x); o[5] = (short)f2bf(b.y); o[6] = (short)f2bf(b.z); o[7] = (short)f2bf(b.w);
  *((short8*)out + i) = o;
}

// ---------------- transpose+convert weights: (L,K,N) f32 -> (L,N,K) bf16 ----------------
__global__ __launch_bounds__(256) void k_transw(const float* __restrict__ in,
                                                unsigned short* __restrict__ out) {
  __shared__ float Tt[32][33];
  int k0 = blockIdx.x * 32, n0 = blockIdx.y * 32, l = blockIdx.z;
  const float* ip = in + (size_t)l * 1024 * 4096;
  unsigned short* op = out + (size_t)l * 4096 * 1024;
  int r = threadIdx.x >> 5, c = threadIdx.x & 31;
  for (int rr = r; rr < 32; rr += 8)
    Tt[rr][c] = ip[(size_t)(k0 + rr) * 4096 + n0 + c];
  __syncthreads();
  for (int rr = r; rr < 32; rr += 8)
    op[(size_t)(n0 + rr) * 1024 + k0 + c] = f2bf(Tt[c][rr]);
}

// ---------------- input-path GEMM (layer 0): Zin0 = X @ Wi0 ----------------
#define PAD 40
__global__ __launch_bounds__(256) void k_gemm_in(const unsigned short* __restrict__ X,
                                                 const unsigned short* __restrict__ WT,
                                                 unsigned short* __restrict__ Z) {
  __shared__ short Al[128 * PAD];
  __shared__ short Bl[128 * PAD];
  int bx = blockIdx.x;
  int m0 = (bx >> 5) * 128, n0 = (bx & 31) * 128;
  int tid = threadIdx.x, lane = tid & 63, wv = tid >> 6;
  int wm = (wv >> 1) * 64, wn = (wv & 1) * 64;
  int l15 = lane & 15, lh = lane >> 4;
  f32x4 acc[4][4] = {};
  for (int s = 0; s < 32; ++s) {
    int k0 = s * 32;
    __syncthreads();
    for (int rr = 0; rr < 2; ++rr) {
      int ch = rr * 256 + tid;
      int row = ch >> 2, ko = (ch & 3) * 8;
      *(short8*)&Al[row * PAD + ko] = *(const short8*)&X[(size_t)(m0 + row) * 1024 + k0 + ko];
      *(short8*)&Bl[row * PAD + ko] = *(const short8*)&WT[(size_t)(n0 + row) * 1024 + k0 + ko];
    }
    __syncthreads();
    bf16x8 af[4], bfr[4];
    for (int mi = 0; mi < 4; ++mi)
      af[mi] = *(const bf16x8*)&Al[(wm + mi * 16 + l15) * PAD + lh * 8];
    for (int ni = 0; ni < 4; ++ni)
      bfr[ni] = *(const bf16x8*)&Bl[(wn + ni * 16 + l15) * PAD + lh * 8];
    for (int mi = 0; mi < 4; ++mi)
      for (int ni = 0; ni < 4; ++ni)
        acc[mi][ni] = __builtin_amdgcn_mfma_f32_16x16x32_bf16(af[mi], bfr[ni], acc[mi][ni], 0, 0, 0);
  }
  for (int mi = 0; mi < 4; ++mi)
    for (int ni = 0; ni < 4; ++ni)
      for (int r2 = 0; r2 < 4; ++r2) {
        int row = m0 + wm + mi * 16 + (lane >> 4) * 4 + r2;
        int col = n0 + wn + ni * 16 + l15;
        Z[(size_t)row * 4096 + col] = f2bf(acc[mi][ni][r2]);
      }
}

// ================== recurrent WG body: 32 WGs per layer, one XCD (fast path) ==================
// Local h ring: plain write-through stores + plain cached loads; freshness by ring depth 16
// + agent-acquire fence every 8 steps (proven scheme). Local flags: plain store + atomic-RMW
// poll at the XCD L2. Fallback FB=true: everything via MALL (round-8 proven).
template<int LAY, bool FB>
__device__ void rec_body(const unsigned short* __restrict__ WhT,
                         const unsigned short* __restrict__ Zin0,
                         const float* __restrict__ bias, uint8_t* W,
                         float* __restrict__ yout, float* __restrict__ hT,
                         float* __restrict__ cT, int wgl, float* zsb) {
  const int tid = threadIdx.x, lane = tid & 63, wv = tid >> 6;
  const int l15 = lane & 15, lh = lane >> 4;
  const int kw = wv & 3, nw = wv >> 2;
  const int U = wgl * 32;

  // ---- weights -> registers (once): 32 bf16x8 frags/lane ----
  bf16x8 bw[32];
  const unsigned short* WhL = WhT + (size_t)LAY * 4096 * 1024;
#pragma unroll
  for (int nt = 0; nt < 4; ++nt) {
    int c = nw * 64 + nt * 16 + l15;
    int row = (c >> 5) * 1024 + U + (c & 31);
#pragma unroll
    for (int kf = 0; kf < 8; ++kf)
      bw[nt * 8 + kf] = *(const bf16x8*)&WhL[(size_t)row * 1024 + kw * 256 + kf * 32 + lh * 8];
  }
#pragma unroll
  for (int i = 0; i < 32; ++i) asm volatile("" : "+v"(bw[i]));

  const int b = tid >> 4, j2 = (tid & 15) * 2;
  const int u0 = U + j2;
  const float* biasL = bias + LAY * 4096;
  float bz[2][4];
#pragma unroll
  for (int g = 0; g < 4; ++g) {
    bz[0][g] = biasL[g * 1024 + u0];
    bz[1][g] = biasL[g * 1024 + u0 + 1];
  }
  float cs0 = 0.f, cs1 = 0.f;

  unsigned short* lring = (unsigned short*)(W + LRING_OFF + (size_t)LAY * 0x100000);
  unsigned short* xring = (unsigned short*)(W + XRING_OFF + (size_t)(LAY < 2 ? LAY : 0) * 0x100000);
  const float* zring = (const float*)(W + ZRING_OFF + (size_t)(LAY > 0 ? LAY - 1 : 0) * 0x800000);
  u32* floc = (u32*)(W + FLOC_OFF + LAY * 0x800);
  u32* fcrs = (u32*)(W + FCRS_OFF + LAY * 0x800);
  u32* fing_in = (u32*)(W + FING_OFF + (LAY > 0 ? LAY - 1 : 0) * 0x800);
  u32* fing_dn = (u32*)(W + FING_OFF + (LAY < 2 ? LAY : 0) * 0x800);
  u32 fseen = 0;

  for (int t = 0; t < T_; ++t) {
    // ---- L0 Zin prefetch (static buffer, overlaps polls) ----
    u32 zp[4] = {0, 0, 0, 0};
    if (LAY == 0) {
      const unsigned short* zr = Zin0 + (size_t)(b * T_ + t) * 4096 + u0;
#pragma unroll
      for (int g = 0; g < 4; ++g) zp[g] = *(const u32*)&zr[g * 1024];
    }
    // ---- own-layer step barrier (wave 0) ----
    if (t > 0 && wv == 0) {
      u32* fp = floc + (lane & 31) * 16;
      for (;;) {
        u32 f = FB ? ld_mall(fp) : poll_loc(fp);
        if (__all((int)(f >= (u32)t))) break;
        __builtin_amdgcn_s_sleep(1);
      }
      if ((t & 7) == 0)
        __builtin_amdgcn_fence(__ATOMIC_ACQUIRE, "agent");  // ring-reuse freshness
    }
    // ---- Zin availability (wave 1; skip when already ahead) ----
    if (LAY > 0 && wv == 1 && fseen < (u32)(t + 1)) {
      u32* fp = fing_in + wgl * 16;
      for (;;) {
        u32 f = ld_mall(fp);
        if (__all((int)(f >= (u32)(t + 1)))) { fseen = f; break; }
        __builtin_amdgcn_s_sleep(1);
      }
    }
    __syncthreads();

    // ---- Zin ring loads (fresh slot addresses; L2-shared per XCD) ----
    u64 zq[4] = {0, 0, 0, 0};
    if (LAY > 0) {
      const float* zs0 = zring + (size_t)(t & 15) * 131072 + (size_t)b * 4096 + wgl * 32 + j2;
#pragma unroll
      for (int g = 0; g < 4; ++g) zq[g] = *(const u64*)(zs0 + g * 1024);
    }
    // ---- recurrent GEMM on h(t-1) from local ring ----
    f32x4 acc[2][4] = {};
    if (t > 0) {
      const unsigned short* base = lring + (size_t)((t - 1) & 15) * 32768;
#pragma unroll
      for (int kf = 0; kf < 8; ++kf) {
        int kk = kw * 256 + kf * 32 + lh * 8;
        const unsigned short* pa = base + (kk >> 2) * 128 + l15 * 4;
        u64 x0 = *(const u64*)(pa);
        u64 x1 = *(const u64*)(pa + 128);
        u64 x2 = *(const u64*)(pa + 64);
        u64 x3 = *(const u64*)(pa + 192);
        bf16x8 a0, a1;
        ((u64*)&a0)[0] = x0; ((u64*)&a0)[1] = x1;
        ((u64*)&a1)[0] = x2; ((u64*)&a1)[1] = x3;
#pragma unroll
        for (int nt = 0; nt < 4; ++nt) {
          acc[0][nt] = __builtin_amdgcn_mfma_f32_16x16x32_bf16(a0, bw[nt * 8 + kf], acc[0][nt], 0, 0, 0);
          acc[1][nt] = __builtin_amdgcn_mfma_f32_16x16x32_bf16(a1, bw[nt * 8 + kf], acc[1][nt], 0, 0, 0);
        }
      }
    }
    // ---- split-K partials: [kw*2+mt][nw*4+nt][lane][reg] ----
#pragma unroll
    for (int mt = 0; mt < 2; ++mt)
#pragma unroll
      for (int nt = 0; nt < 4; ++nt)
        *(f32x4*)&zsb[(((kw * 2 + mt) * 8) + nw * 4 + nt) * 256 + lane * 4] = acc[mt][nt];
    __syncthreads();

    // ---- reduce 4 K-partials + gates, 2 cells/thread ----
    float hv0, hv1;
    {
      const int mt = b >> 4, lh2 = (b & 15) >> 2, r = b & 3;
      float hvv[2];
#pragma unroll
      for (int cell = 0; cell < 2; ++cell) {
        int j = j2 + cell;
        float z[4];
#pragma unroll
        for (int g = 0; g < 4; ++g) {
          int c = g * 32 + j;
          int idx = (mt * 8 + (c >> 6) * 4 + ((c >> 4) & 3)) * 256 + (lh2 * 16 + (c & 15)) * 4 + r;
          float s = zsb[idx];
#pragma unroll
          for (int kq = 1; kq < 4; ++kq) s += zsb[idx + kq * 4096];
          float zin;
          if (LAY == 0) zin = bf2f((unsigned short)(cell ? (zp[g] >> 16) : (zp[g] & 0xffffu)));
          else { float2 f2v = *(float2*)&zq[g]; zin = cell ? f2v.y : f2v.x; }
          z[g] = s + zin + bz[cell][g];
        }
        float ig = sigm(z[0]), fg = sigm(z[1]), gg = tanh_(z[2]), og = sigm(z[3]);
        float& cs = cell ? cs1 : cs0;
        cs = fg * cs + ig * gg;
        hvv[cell] = og * tanh_(cs);
      }
      hv0 = hvv[0]; hv1 = hvv[1];
    }
    // ---- publish h ----
    u32 hd = (u32)f2bf(hv0) | ((u32)f2bf(hv1) << 16);
    size_t hoff = (size_t)(u0 >> 2) * 128 + b * 4 + (u0 & 3);
    if (FB) st_wt32(lring + (size_t)(t & 15) * 32768 + hoff, hd);
    else    *(u32*)(lring + (size_t)(t & 15) * 32768 + hoff) = hd;  // write-through to local L2
    if (LAY < 2) st_wt32(xring + (size_t)(t & 15) * 32768 + hoff, hd);
    asm volatile("s_waitcnt vmcnt(0)" ::: "memory");
    __syncthreads();
    if (tid == 0) {
      if (FB) st_mallf(&floc[wgl * 16], (u32)(t + 1));
      else    *(volatile u32*)&floc[wgl * 16] = (u32)(t + 1);   // write-through; pollers RMW at L2
    }
    if ((t & 3) == 3) {  // cross publish (xring stores already drained) + back-pressure
      if (tid == 0) st_mallf(&fcrs[wgl * 16], (u32)(t + 1));
      if (LAY < 2 && t >= 12 && wv == 0) {
        u32* fp = fing_dn + (lane & 31) * 16;
        for (;;) {
          u32 f = ld_mall(fp);
          if (__all((int)(f >= (u32)(t - 8)))) break;
          __builtin_amdgcn_s_sleep(1);
        }
      }
      __syncthreads();
    }
    // ---- off-critical-path outputs ----
    if (LAY == 2) {
      float fv[2] = {hv0, hv1};
      u64 yv; __builtin_memcpy(&yv, fv, 8);
      __builtin_nontemporal_store(yv, (u64*)&yout[(size_t)(b * T_ + t) * 1024 + u0]);
    }
    if (t == T_ - 1) {
      hT[LAY * (B_ * 1024) + b * 1024 + u0] = hv0;
      hT[LAY * (B_ * 1024) + b * 1024 + u0 + 1] = hv1;
      cT[LAY * (B_ * 1024) + b * 1024 + u0] = cs0;
      cT[LAY * (B_ * 1024) + b * 1024 + u0 + 1] = cs1;
    }
  }
}

// ================== feed-forward input-GEMM: Zin_lc(t) = h_{lc-1}(t) @ Wi_lc ==================
template<int LC>
__device__ void ing_body(const unsigned short* __restrict__ WiT, uint8_t* W, int w, float* zsb) {
  const int tid = threadIdx.x, lane = tid & 63, wv = tid >> 6;
  const int l15 = lane & 15, lh = lane >> 4;
  const int kw = wv & 3, nw = wv >> 2;

  bf16x8 bw[32];
  const unsigned short* WiL = WiT + (size_t)LC * 4096 * 1024;
#pragma unroll
  for (int nt = 0; nt < 4; ++nt) {
    int c = nw * 64 + nt * 16 + l15;
    int row = (c >> 5) * 1024 + w * 32 + (c & 31);
#pragma unroll
    for (int kf = 0; kf < 8; ++kf)
      bw[nt * 8 + kf] = *(const bf16x8*)&WiL[(size_t)row * 1024 + kw * 256 + kf * 32 + lh * 8];
  }
#pragma unroll
  for (int i = 0; i < 32; ++i) asm volatile("" : "+v"(bw[i]));

  const int b = tid >> 4, j2 = (tid & 15) * 2;
  const unsigned short* xin = (const unsigned short*)(W + XRING_OFF + (size_t)(LC - 1) * 0x100000);
  float* zring = (float*)(W + ZRING_OFF + (size_t)(LC - 1) * 0x800000);
  u32* fup = (u32*)(W + FCRS_OFF + (LC - 1) * 0x800);
  u32* fcons = (u32*)(W + FCRS_OFF + LC * 0x800);
  u32* fme = (u32*)(W + FING_OFF + (LC - 1) * 0x800);
  const int mt = b >> 4, lh2 = (b & 15) >> 2, r = b & 3;

  for (int k4 = 0; k4 < 128; ++k4) {
    if (wv == 0) {  // upstream h ready through t = 4k4+3
      u32* fp = fup + (lane & 31) * 16;
      for (;;) {
        u32 f = ld_mall(fp);
        if (__all((int)(f >= (u32)(4 * k4 + 4)))) break;
        __builtin_amdgcn_s_sleep(1);
      }
      if (k4 > 0 && (k4 & 1) == 0)
        __builtin_amdgcn_fence(__ATOMIC_ACQUIRE, "agent");  // ring-reuse freshness
    }
    if (wv == 1 && k4 >= 3) {  // consumer back-pressure (ring depth 16)
      u32* fp = fcons + (lane & 31) * 16;
      for (;;) {
        u32 f = ld_mall(fp);
        if (__all((int)(f >= (u32)(4 * k4 - 8)))) break;
        __builtin_amdgcn_s_sleep(1);
      }
    }
    __syncthreads();
#pragma unroll 1
    for (int q = 0; q < 4; ++q) {
      int t = k4 * 4 + q;
      const unsigned short* base = xin + (size_t)(t & 15) * 32768;
      f32x4 acc[2][4] = {};
#pragma unroll
      for (int kf = 0; kf < 8; ++kf) {
        int kk = kw * 256 + kf * 32 + lh * 8;
        const unsigned short* pa = base + (kk >> 2) * 128 + l15 * 4;
        u64 x0 = *(const u64*)(pa);
        u64 x1 = *(const u64*)(pa + 128);
        u64 x2 = *(const u64*)(pa + 64);
        u64 x3 = *(const u64*)(pa + 192);
        bf16x8 a0, a1;
        ((u64*)&a0)[0] = x0; ((u64*)&a0)[1] = x1;
        ((u64*)&a1)[0] = x2; ((u64*)&a1)[1] = x3;
#pragma unroll
        for (int nt = 0; nt < 4; ++nt) {
          acc[0][nt] = __builtin_amdgcn_mfma_f32_16x16x32_bf16(a0, bw[nt * 8 + kf], acc[0][nt], 0, 0, 0);
          acc[1][nt] = __builtin_amdgcn_mfma_f32_16x16x32_bf16(a1, bw[nt * 8 + kf], acc[1][nt], 0, 0, 0);
        }
      }
#pragma unroll
      for (int mtq = 0; mtq < 2; ++mtq)
#pragma unroll
        for (int nt = 0; nt < 4; ++nt)
          *(f32x4*)&zsb[(((kw * 2 + mtq) * 8) + nw * 4 + nt) * 256 + lane * 4] = acc[mtq][nt];
      __syncthreads();
      // reduce + f32 write-through to Zin ring (MALL)
      float* zdst = zring + (size_t)(t & 15) * 131072 + (size_t)b * 4096 + w * 32 + j2;
#pragma unroll
      for (int g = 0; g < 4; ++g) {
        float zz[2];
#pragma unroll
        for (int cell = 0; cell < 2; ++cell) {
          int c = g * 32 + j2 + cell;
          int idx = (mt * 8 + (c >> 6) * 4 + ((c >> 4) & 3)) * 256 + (lh2 * 16 + (c & 15)) * 4 + r;
          float s = zsb[idx];
#pragma unroll
          for (int kq = 1; kq < 4; ++kq) s += zsb[idx + kq * 4096];
          zz[cell] = s;
        }
        u64 zv; __builtin_memcpy(&zv, zz, 8);
        st_wt64(zdst + (size_t)g * 1024, zv);
      }
      __syncthreads();
    }
    asm volatile("s_waitcnt vmcnt(0)" ::: "memory");
    __syncthreads();
    if (tid == 0) st_mallf(&fme[w * 16], (u32)(4 * k4 + 4));
  }
}

__global__ __launch_bounds__(512)
__attribute__((amdgpu_waves_per_eu(2, 2)))
void k_rec3(const unsigned short* __restrict__ WiT, const unsigned short* __restrict__ WhT,
            const unsigned short* __restrict__ Zin0, const float* __restrict__ bias,
            uint8_t* __restrict__ W, float* __restrict__ yout,
            float* __restrict__ hT, float* __restrict__ cT) {
  extern __shared__ float zsb[];  // 64KB
  __shared__ u32 fbsh;
  const int bid = blockIdx.x, role = bid & 7, wgl = bid >> 3, tid = threadIdx.x;
  u32* ctl = (u32*)(W + CTL_OFF);

  // ---- startup: co-location check + global fallback agreement (proven agent atomics) ----
  if (tid == 0) {
    u32 myx;
    asm volatile("s_getreg_b32 %0, hwreg(HW_REG_XCC_ID)" : "=s"(myx));
    if (role < 3 && wgl == 0)
      __hip_atomic_store(&ctl[4 + role], myx + 1u, __ATOMIC_RELAXED, __HIP_MEMORY_SCOPE_AGENT);
    __hip_atomic_fetch_add(&ctl[0], 1u, __ATOMIC_ACQ_REL, __HIP_MEMORY_SCOPE_AGENT);
    while (__hip_atomic_load(&ctl[0], __ATOMIC_ACQUIRE, __HIP_MEMORY_SCOPE_AGENT) < 256u)
      __builtin_amdgcn_s_sleep(2);
    if (role < 3) {
      u32 lx = __hip_atomic_load(&ctl[4 + role], __ATOMIC_RELAXED, __HIP_MEMORY_SCOPE_AGENT);
      if (lx != myx + 1u)
        __hip_atomic_store(&ctl[2], 1u, __ATOMIC_RELAXED, __HIP_MEMORY_SCOPE_AGENT);
    }
    __hip_atomic_fetch_add(&ctl[1], 1u, __ATOMIC_ACQ_REL, __HIP_MEMORY_SCOPE_AGENT);
    while (__hip_atomic_load(&ctl[1], __ATOMIC_ACQUIRE, __HIP_MEMORY_SCOPE_AGENT) < 256u)
      __builtin_amdgcn_s_sleep(2);
    fbsh = __hip_atomic_load(&ctl[2], __ATOMIC_RELAXED, __HIP_MEMORY_SCOPE_AGENT);
  }
  __syncthreads();
  const bool fb = (fbsh != 0u);

  if (role == 0) {
    if (fb) rec_body<0, true>(WhT, Zin0, bias, W, yout, hT, cT, wgl, zsb);
    else    rec_body<0, false>(WhT, Zin0, bias, W, yout, hT, cT, wgl, zsb);
  } else if (role == 1) {
    if (fb) rec_body<1, true>(WhT, Zin0, bias, W, yout, hT, cT, wgl, zsb);
    else    rec_body<1, false>(WhT, Zin0, bias, W, yout, hT, cT, wgl, zsb);
  } else if (role == 2) {
    if (fb) rec_body<2, true>(WhT, Zin0, bias, W, yout, hT, cT, wgl, zsb);
    else    rec_body<2, false>(WhT, Zin0, bias, W, yout, hT, cT, wgl, zsb);
  } else if (role == 3) {
    ing_body<1>(WiT, W, wgl, zsb);
  } else if (role == 4) {
    ing_body<2>(WiT, W, wgl, zsb);
  }
  // roles 5-7: exit after startup barrier
}

extern "C" void kernel_launch(void* const* d_in, const int* in_sizes, int n_in,
                              void* d_out, int out_size, void* d_ws, size_t ws_size,
                              hipStream_t stream) {
  const float* x = (const float*)d_in[0];
  const float* Wi = (const float*)d_in[1];
  const float* Wh = (const float*)d_in[2];
  const float* bias = (const float*)d_in[3];
  float* out = (float*)d_out;
  uint8_t* W = (uint8_t*)d_ws;

  unsigned short* Zin0 = (unsigned short*)(W + ZIN0_OFF);
  unsigned short* Xa = (unsigned short*)(W + XA_OFF);
  unsigned short* WiT = (unsigned short*)(W + WIT_OFF);
  unsigned short* WhT = (unsigned short*)(W + WHT_OFF);

  hipMemsetAsync(W, 0, 0x8000, stream);  // ctl + all flag arrays
  k_conv<<<8192, 256, 0, stream>>>(x, Xa, (B_ * T_ * 1024) / 8);
  k_transw<<<dim3(32, 128, 3), 256, 0, stream>>>(Wi, WiT);
  k_transw<<<dim3(32, 128, 3), 256, 0, stream>>>(Wh, WhT);
  k_gemm_in<<<4096, 256, 0, stream>>>(Xa, WiT, Zin0);

  float* yout = out;
  float* hT = out + 16777216;
  float* cT = out + 16777216 + 98304;
  k_rec3<<<256, 512, 65536, stream>>>(WiT, WhT, Zin0, bias, W, yout, hT, cT);
}

// Round 11
// 3844.682 us; speedup vs baseline: 1.2306x; 1.2306x over previous
//
#include <hip/hip_runtime.h>
#include <hip/hip_bf16.h>
#include <stdint.h>

typedef __bf16 bf16x8 __attribute__((ext_vector_type(8)));
typedef float f32x4 __attribute__((ext_vector_type(4)));
typedef short short8 __attribute__((ext_vector_type(8)));
typedef unsigned long long u64;
typedef unsigned int u32;

#define B_ 32
#define T_ 512
#define D_ 1024
#define NG 4096
#define L_ 3
#define HD 32            // rotating h step-buffer depth
#define HSLOT 32768      // ushorts per slot (32 batches x 1024 units)
#define NWG3 192

__device__ inline unsigned short f2bf(float f) {
  unsigned u = __float_as_uint(f);
  unsigned r = (u + 0x7fffu + ((u >> 16) & 1u)) >> 16;
  return (unsigned short)r;
}
__device__ inline float bf2f(unsigned short h) {
  return __uint_as_float(((unsigned)h) << 16);
}
__device__ __forceinline__ float sigm(float x) { return 1.f / (1.f + __expf(-x)); }
__device__ __forceinline__ float tanh_(float x) {
  float e2 = __expf(-2.f * fabsf(x));
  return copysignf((1.f - e2) / (1.f + e2), x);
}
__device__ __forceinline__ u32 ld_mall(const u32* p) {
  return __hip_atomic_load(p, __ATOMIC_RELAXED, __HIP_MEMORY_SCOPE_AGENT);
}

// ---------------- f32 -> bf16 convert (vectorized) ----------------
__global__ __launch_bounds__(256) void k_conv(const float* __restrict__ in,
                                              unsigned short* __restrict__ out, int n8) {
  int i = blockIdx.x * 256 + threadIdx.x;
  if (i >= n8) return;
  const float4* p = (const float4*)(in) + (size_t)i * 2;
  float4 a = p[0], b = p[1];
  short8 o;
  o[0] = (short)f2bf(a.x); o[1] = (short)f2bf(a.y); o[2] = (short)f2bf(a.z); o[3] = (short)f2bf(a.w);
  o[4] = (short)f2bf(b.x); o[5] = (short)f2bf(b.y); o[6] = (short)f2bf(b.z); o[7] = (short)f2bf(b.w);
  *((short8*)out + i) = o;
}

// ---------------- transpose+convert weights: (L,K,N) f32 -> (L,N,K) bf16 ----------------
__global__ __launch_bounds__(256) void k_transw(const float* __restrict__ in,
                                                unsigned short* __restrict__ out) {
  __shared__ float Tt[32][33];
  int k0 = blockIdx.x * 32, n0 = blockIdx.y * 32, l = blockIdx.z;
  const float* ip = in + (size_t)l * D_ * NG;
  unsigned short* op = out + (size_t)l * NG * D_;
  int r = threadIdx.x >> 5, c = threadIdx.x & 31;
  for (int rr = r; rr < 32; rr += 8)
    Tt[rr][c] = ip[(size_t)(k0 + rr) * NG + n0 + c];
  __syncthreads();
  for (int rr = r; rr < 32; rr += 8)
    op[(size_t)(n0 + rr) * D_ + k0 + c] = f2bf(Tt[c][rr]);
}

// ---------------- input-path GEMM (layer 0 only): Z = X @ Wi0 ----------------
#define PAD 40
__global__ __launch_bounds__(256) void k_gemm_in(const unsigned short* __restrict__ X,
                                                 const unsigned short* __restrict__ WT,
                                                 unsigned short* __restrict__ Z) {
  __shared__ short Al[128 * PAD];
  __shared__ short Bl[128 * PAD];
  int bx = blockIdx.x;
  int m0 = (bx >> 5) * 128, n0 = (bx & 31) * 128;
  int tid = threadIdx.x, lane = tid & 63, wv = tid >> 6;
  int wm = (wv >> 1) * 64, wn = (wv & 1) * 64;
  int l15 = lane & 15, lh = lane >> 4;
  f32x4 acc[4][4] = {};
  for (int s = 0; s < 32; ++s) {
    int k0 = s * 32;
    __syncthreads();
    for (int rr = 0; rr < 2; ++rr) {
      int ch = rr * 256 + tid;
      int row = ch >> 2, ko = (ch & 3) * 8;
      *(short8*)&Al[row * PAD + ko] = *(const short8*)&X[(size_t)(m0 + row) * 1024 + k0 + ko];
      *(short8*)&Bl[row * PAD + ko] = *(const short8*)&WT[(size_t)(n0 + row) * 1024 + k0 + ko];
    }
    __syncthreads();
    bf16x8 af[4], bfr[4];
    for (int mi = 0; mi < 4; ++mi)
      af[mi] = *(const bf16x8*)&Al[(wm + mi * 16 + l15) * PAD + lh * 8];
    for (int ni = 0; ni < 4; ++ni)
      bfr[ni] = *(const bf16x8*)&Bl[(wn + ni * 16 + l15) * PAD + lh * 8];
    for (int mi = 0; mi < 4; ++mi)
      for (int ni = 0; ni < 4; ++ni)
        acc[mi][ni] = __builtin_amdgcn_mfma_f32_16x16x32_bf16(af[mi], bfr[ni], acc[mi][ni], 0, 0, 0);
  }
  for (int mi = 0; mi < 4; ++mi)
    for (int ni = 0; ni < 4; ++ni)
      for (int r2 = 0; r2 < 4; ++r2) {
        int row = m0 + wm + mi * 16 + (lane >> 4) * 4 + r2;
        int col = n0 + wn + ni * 16 + l15;
        Z[(size_t)row * NG + col] = f2bf(acc[mi][ni][r2]);
      }
}

// ---------------- fused wavefronted 3-layer persistent recurrent kernel ----------------
// Round-11 changes vs the proven round-7 skeleton:
//  * 2-step layer skew (implicit: each layer free-runs on flags; flags carry per-layer t).
//  * No top-of-step join. Waves 0-3 (x-GEMM, LAY>0) poll ONLY the upstream flag
//    (>= t+1, ~2 steps stale -> usually instantly satisfied; shfl-min cache skips the
//    poll entirely when known-ahead) then immediately load+MFMA the x half. Waves 4-7
//    (and all 8 for LAY0) poll own-layer flags (>= t) then load+MFMA own-h. The x path
//    thus fully overlaps the own-chain wait, collapsing the period to the own-chain.
//  * Backpressure every 16 steps (down >= t-8; slot-gap bound 24 < HD=32).
//  * Unified join+acquire-fence every 32 steps (ring-reuse freshness, proven cadence).
template<int LAY>
__device__ __forceinline__ void rec_body(
    const unsigned short* __restrict__ WiL, const unsigned short* __restrict__ WhL,
    const unsigned short* __restrict__ Zin0, const float* __restrict__ biasL,
    unsigned short* __restrict__ hh, unsigned int* __restrict__ flags,
    float* __restrict__ yout, float* __restrict__ hT, float* __restrict__ cT,
    int wgl, float* zsb) {
  int tid = threadIdx.x, lane = tid & 63, kw = tid >> 6;
  int l15 = lane & 15, lh = lane >> 4;
  int U = wgl * 16;
  constexpr int NKF = (LAY == 0) ? 4 : 8;   // K-frags per wave (kspan = NKF*32)

  // ---- load this wave's weight B-fragments (register-resident) ----
  bf16x8 bw[4 * NKF];
  {
    const unsigned short* Wsrc;
    int k0;
    if (LAY == 0) { Wsrc = WhL; k0 = kw * 128; }
    else { Wsrc = (kw < 4) ? WiL : WhL; k0 = (kw & 3) * 256; }
#pragma unroll
    for (int nt = 0; nt < 4; ++nt)
#pragma unroll
      for (int kf = 0; kf < NKF; ++kf)
        bw[nt * NKF + kf] =
            *(const bf16x8*)&Wsrc[(size_t)(nt * 1024 + U + l15) * 1024 + k0 + kf * 32 + lh * 8];
  }
#pragma unroll
  for (int i = 0; i < 4 * NKF; ++i) asm volatile("" : "+v"(bw[i]));

  // elementwise cell: thread -> (batch b, unit j)
  int b = tid >> 4, j = tid & 15;
  int u = U + j;
  float bz0 = biasL[u], bz1 = biasL[1024 + u], bz2 = biasL[2048 + u], bz3 = biasL[3072 + u];
  float cst = 0.f;
  unsigned short* hhme = hh + (size_t)LAY * HD * HSLOT;
  const unsigned short* hhin = (LAY == 0) ? hhme : hh + (size_t)(LAY - 1) * HD * HSLOT;
  u32 fminup = 0;  // shfl-min cache of upstream flag (waves 0-3, LAY>0)

  for (int t = 0; t < T_; ++t) {
    // ---- Zin0 prefetch (layer 0 only; overlaps polls) ----
    unsigned short zv0 = 0, zv1 = 0, zv2 = 0, zv3 = 0;
    if (LAY == 0) {
      const unsigned short* zr = Zin0 + (size_t)(b * T_ + t) * NG + u;
      zv0 = zr[0]; zv1 = zr[1024]; zv2 = zr[2048]; zv3 = zr[3072];
    }
    const bool fence_step = (t > 0) && ((t & 31) == 0);
    if (fence_step) {
      // unified join: wave 0 polls own (+backpressure), wave 1 polls upstream; fence; join
      if (kw == 0) {
        const u32* fp = flags + LAY * 64 + lane;
        for (;;) {
          u32 f = ld_mall(fp);
          if (__all((int)(f >= (u32)t))) break;
          __builtin_amdgcn_s_sleep(1);
        }
        if (LAY < 2) {
          const u32* fd = flags + (LAY + 1) * 64 + lane;
          u32 need = (t >= 8) ? (u32)(t - 8) : 0u;
          for (;;) {
            u32 f = ld_mall(fd);
            if (__all((int)(f >= need))) break;
            __builtin_amdgcn_s_sleep(1);
          }
        }
        __builtin_amdgcn_fence(__ATOMIC_ACQUIRE, "agent");
      }
      if (LAY > 0 && kw == 1) {
        const u32* fp = flags + (LAY - 1) * 64 + lane;
        for (;;) {
          u32 f = ld_mall(fp);
          if (__all((int)(f >= (u32)(t + 1)))) break;
          __builtin_amdgcn_s_sleep(1);
        }
      }
      __syncthreads();
    } else {
      // per-wave dependency-specific polls, no join
      if (LAY > 0 && kw < 4) {
        if (fminup < (u32)(t + 1)) {
          const u32* fp = flags + (LAY - 1) * 64 + lane;
          u32 f;
          for (;;) {
            f = ld_mall(fp);
            if (__all((int)(f >= (u32)(t + 1)))) break;
            __builtin_amdgcn_s_sleep(1);
          }
          u32 m = f;
#pragma unroll
          for (int o = 32; o >= 1; o >>= 1) {
            u32 x2 = (u32)__shfl_xor((int)m, o);
            m = m < x2 ? m : x2;
          }
          fminup = m;
        }
      }
      if (t > 0 && (LAY == 0 || kw >= 4)) {
        const u32* fp = flags + LAY * 64 + lane;
        for (;;) {
          u32 f = ld_mall(fp);
          if (__all((int)(f >= (u32)t))) break;
          __builtin_amdgcn_s_sleep(1);
        }
      }
    }

    // ---- GEMM: this wave's K-slice (unconditional; slot HD-1 zeroed for t==0) ----
    {
      const unsigned short* hsrc;
      if (LAY == 0)      hsrc = hhme + (size_t)((t - 1) & (HD - 1)) * HSLOT;
      else if (kw < 4)   hsrc = hhin + (size_t)(t & (HD - 1)) * HSLOT;
      else               hsrc = hhme + (size_t)((t - 1) & (HD - 1)) * HSLOT;
      f32x4 acc[2][4] = {};
#pragma unroll
      for (int kf = 0; kf < NKF; ++kf) {
        int k = (LAY == 0 ? kw * 128 : (kw & 3) * 256) + kf * 32 + lh * 8;
        const unsigned short* pa = hsrc + (k >> 2) * 128;
        u64 x0 = *(const u64*)(pa + l15 * 4);
        u64 x1 = *(const u64*)(pa + 128 + l15 * 4);
        u64 x2 = *(const u64*)(pa + 64 + l15 * 4);
        u64 x3 = *(const u64*)(pa + 192 + l15 * 4);
        bf16x8 a0, a1;
        ((u64*)&a0)[0] = x0; ((u64*)&a0)[1] = x1;
        ((u64*)&a1)[0] = x2; ((u64*)&a1)[1] = x3;
#pragma unroll
        for (int nt = 0; nt < 4; ++nt) {
          acc[0][nt] = __builtin_amdgcn_mfma_f32_16x16x32_bf16(a0, bw[nt * NKF + kf], acc[0][nt], 0, 0, 0);
          acc[1][nt] = __builtin_amdgcn_mfma_f32_16x16x32_bf16(a1, bw[nt * NKF + kf], acc[1][nt], 0, 0, 0);
        }
      }
      // ---- write split-K partials: zs[kw][mt*4+nt][lane][4] ----
#pragma unroll
      for (int mt = 0; mt < 2; ++mt)
#pragma unroll
        for (int nt = 0; nt < 4; ++nt)
          *(f32x4*)&zsb[(((kw * 8) + mt * 4 + nt) * 64 + lane) * 4] = acc[mt][nt];
    }
    // ---- backpressure (kw==0, every 16 steps, non-fence; before the join) ----
    if (LAY < 2 && kw == 0 && t >= 16 && (t & 15) == 0 && (t & 31) != 0) {
      const u32* fd = flags + (LAY + 1) * 64 + lane;
      u32 need = (u32)(t - 8);
      for (;;) {
        u32 f = ld_mall(fd);
        if (__all((int)(f >= need))) break;
        __builtin_amdgcn_s_sleep(1);
      }
    }
    __syncthreads();   // sync_A: all partials in zsb
    // ---- reduce 8 partials + gates + state update ----
    float hv;
    {
      int mt = b >> 4, lzs = ((b & 15) >> 2) * 16 + j, r = b & 3;
      float z0 = bz0, z1 = bz1, z2 = bz2, z3 = bz3;
#pragma unroll
      for (int k2 = 0; k2 < 8; ++k2) {
        int base = ((k2 * 8 + mt * 4) * 64 + lzs) * 4 + r;
        z0 += zsb[base];
        z1 += zsb[base + 256];
        z2 += zsb[base + 512];
        z3 += zsb[base + 768];
      }
      if (LAY == 0) { z0 += bf2f(zv0); z1 += bf2f(zv1); z2 += bf2f(zv2); z3 += bf2f(zv3); }
      float ig = sigm(z0), fg = sigm(z1), gg = tanh_(z2), og = sigm(z3);
      cst = fg * cst + ig * gg;
      hv = og * tanh_(cst);
      unsigned short hw = f2bf(hv);
      unsigned short* ha = hhme + (size_t)(t & (HD - 1)) * HSLOT + (u >> 2) * 128 + b * 4 + (u & 3);
      unsigned hw32 = hw;
      asm volatile("global_store_short %0, %1, off sc0 sc1" :: "v"(ha), "v"(hw32) : "memory");
    }
    // drain h-stores only, then signal
    asm volatile("s_waitcnt vmcnt(0)" ::: "memory");
    __syncthreads();   // sync_B: h complete; also protects zsb reuse next step
    if (tid == 0)
      __hip_atomic_store(&flags[LAY * 64 + wgl], (u32)(t + 1), __ATOMIC_RELAXED,
                         __HIP_MEMORY_SCOPE_AGENT);
    // ---- off-critical-path output stores ----
    if (LAY == 2) __builtin_nontemporal_store(hv, &yout[(size_t)(b * T_ + t) * 1024 + u]);
    if (t == T_ - 1) {
      hT[LAY * (B_ * 1024) + b * 1024 + u] = hv;
      cT[LAY * (B_ * 1024) + b * 1024 + u] = cst;
    }
  }
}

__global__ __launch_bounds__(512)
__attribute__((amdgpu_waves_per_eu(2, 2)))
void k_rec3(
    const unsigned short* __restrict__ WiT, const unsigned short* __restrict__ WhT,
    const unsigned short* __restrict__ Zin0, const float* __restrict__ bias,
    unsigned short* __restrict__ hh, unsigned int* __restrict__ flags,
    float* __restrict__ yout, float* __restrict__ hT, float* __restrict__ cT) {
  extern __shared__ float zsb[];   // 64KB: [kw][8][64][4] f32
  int wg = blockIdx.x;
  int lay = (wg >= 64) + (wg >= 128);
  int wgl = wg & 63;
  const unsigned short* WiL = WiT + (size_t)lay * NG * 1024;
  const unsigned short* WhL = WhT + (size_t)lay * NG * 1024;
  const float* biasL = bias + lay * NG;
  if (lay == 0)      rec_body<0>(WiL, WhL, Zin0, biasL, hh, flags, yout, hT, cT, wgl, zsb);
  else if (lay == 1) rec_body<1>(WiL, WhL, Zin0, biasL, hh, flags, yout, hT, cT, wgl, zsb);
  else               rec_body<2>(WiL, WhL, Zin0, biasL, hh, flags, yout, hT, cT, wgl, zsb);
}

extern "C" void kernel_launch(void* const* d_in, const int* in_sizes, int n_in,
                              void* d_out, int out_size, void* d_ws, size_t ws_size,
                              hipStream_t stream) {
  const float* x = (const float*)d_in[0];
  const float* Wi = (const float*)d_in[1];
  const float* Wh = (const float*)d_in[2];
  const float* bias = (const float*)d_in[3];
  float* out = (float*)d_out;
  uint8_t* W = (uint8_t*)d_ws;

  unsigned* flags = (unsigned*)W;                                   // 3 x 64 flags
  unsigned short* hh  = (unsigned short*)(W + 0x10000);             // 3 x 32 x 64KB = 6MB
  unsigned short* Zin0 = (unsigned short*)(W + 0x800000);           // 128MB bf16 (B*T,4096)
  unsigned short* Xa  = (unsigned short*)(W + 0x8800000);           // 32MB bf16 (B*T,1024)
  unsigned short* WiT = (unsigned short*)(W + 0xA800000);           // 24MB bf16 (L,4096,1024)
  unsigned short* WhT = (unsigned short*)(W + 0xC000000);           // 24MB (ends 0xD800000)

  hipMemsetAsync(d_ws, 0, 4096, stream);                            // flags
  // zero slot HD-1 (=31) of each layer's h-ring (read as h(-1)=0 at t==0)
  hipMemsetAsync(W + 0x10000 + (size_t)31 * 65536, 0, 65536, stream);
  hipMemsetAsync(W + 0x10000 + (size_t)63 * 65536, 0, 65536, stream);
  hipMemsetAsync(W + 0x10000 + (size_t)95 * 65536, 0, 65536, stream);
  k_conv<<<8192, 256, 0, stream>>>(x, Xa, (B_ * T_ * D_) / 8);
  k_transw<<<dim3(32, 128, 3), 256, 0, stream>>>(Wi, WiT);
  k_transw<<<dim3(32, 128, 3), 256, 0, stream>>>(Wh, WhT);
  k_gemm_in<<<4096, 256, 0, stream>>>(Xa, WiT, Zin0);   // layer 0 input gates

  float* yout = out;
  float* hT = out + 16777216;
  float* cT = out + 16777216 + 98304;
  k_rec3<<<NWG3, 512, 65536, stream>>>(WiT, WhT, Zin0, bias, hh, flags, yout, hT, cT);
}